// Round 6
// baseline (1553.858 us; speedup 1.0000x reference)
//
#include <hip/hip_runtime.h>

#define NROWS 131072   // 32*64*64
#define NC 256
#define EPSV 0.001f

// ---------------- covariance accumulation ----------------
// grid 256 x 1024 threads; each block accumulates 512 rows into S (lower tri)
// and channel sums. 8x8 register tile per thread, 16-row LDS chunks.
// R5: explicit amdgpu_waves_per_eu(4) -> 128-VGPR budget. R1-R4 showed every
// variant pinned under 64 VGPRs (36/52/60) = default 8-waves/SIMD budget;
// __launch_bounds__(1024,4) did NOT raise it (allocator left 68 regs unused
// while spilling). Budget, not promotion, was the spill cause.
__global__ __attribute__((amdgpu_flat_work_group_size(1024, 1024), amdgpu_waves_per_eu(4)))
void cov_accum_kernel(
    const float* __restrict__ x, float* __restrict__ S, float* __restrict__ sums)
{
    __shared__ float tile[16][NC];
    const int tid = threadIdx.x;
    const int ty = tid >> 5;      // 0..31 -> rows i = 8*ty..
    const int tx = tid & 31;      // 0..31 -> cols j = 4*tx+{0..3} and 128+4*tx+{0..3}
    const int i0 = ty * 8;

    float acc[8][8];
#pragma unroll
    for (int u = 0; u < 8; ++u)
#pragma unroll
        for (int v = 0; v < 8; ++v) acc[u][v] = 0.f;

    float csum = 0.f;
    const int row_base = blockIdx.x * 512;
    const int sr = tid >> 6;           // staging row 0..15
    const int sc = (tid & 63) << 2;    // staging col (float4)

    for (int ch = 0; ch < 32; ++ch) {
        const int r0 = row_base + ch * 16;
        float4 v4 = *reinterpret_cast<const float4*>(&x[(size_t)(r0 + sr) * NC + sc]);
        *reinterpret_cast<float4*>(&tile[sr][sc]) = v4;
        __syncthreads();
        if (tid < NC) {
            float s = 0.f;
#pragma unroll
            for (int r = 0; r < 16; ++r) s += tile[r][tid];
            csum += s;
        }
#pragma unroll 2
        for (int r = 0; r < 16; ++r) {
            float4 a0 = *reinterpret_cast<const float4*>(&tile[r][i0]);
            float4 a1 = *reinterpret_cast<const float4*>(&tile[r][i0 + 4]);
            float4 b0 = *reinterpret_cast<const float4*>(&tile[r][tx * 4]);
            float4 b1 = *reinterpret_cast<const float4*>(&tile[r][tx * 4 + 128]);
            float ai[8] = {a0.x, a0.y, a0.z, a0.w, a1.x, a1.y, a1.z, a1.w};
            float bj[8] = {b0.x, b0.y, b0.z, b0.w, b1.x, b1.y, b1.z, b1.w};
#pragma unroll
            for (int u = 0; u < 8; ++u)
#pragma unroll
                for (int v = 0; v < 8; ++v)
                    acc[u][v] = fmaf(ai[u], bj[v], acc[u][v]);
        }
        __syncthreads();
    }

#pragma unroll
    for (int u = 0; u < 8; ++u) {
        const int i = i0 + u;
#pragma unroll
        for (int v = 0; v < 8; ++v) {
            const int j = tx * 4 + (v & 3) + ((v < 4) ? 0 : 128);
            if (i >= j) atomicAdd(&S[i * NC + j], acc[u][v]);
        }
    }
    if (tid < NC) atomicAdd(&sums[tid], csum);
}

// ---------------- finalize covariance ----------------
__global__ void finalize_cov_kernel(const float* __restrict__ S,
                                    const float* __restrict__ sums,
                                    float* __restrict__ A)
{
    const int i = blockIdx.x;
    const int j = threadIdx.x;
    const float n = (float)NROWS;
    const float sv = (i >= j) ? S[i * NC + j] : S[j * NC + i];
    float c = (sv - sums[i] * sums[j] / n) / (n - 1.f);
    c *= (1.f - EPSV);
    if (i == j) c += EPSV;
    A[i * NC + j] = c;
}

// ---------------- Cholesky (single block) ----------------
// Structure: ONE barrier/column; colbuf (double-buffered, diag in slot [NC])
// holds the UNSCALED post-update next column; scaling folded into the rank-1
// via rd = 1/diag; colbuf entries i<=k zeroed so the update self-masks.
// 8x8 tile = 64 named scalars (R4). R5: waves_per_eu(4) for the 128-VGPR
// budget (see cov_accum comment — the 64-reg default budget was the spiller).
#define CH_DECL(u) float a##u##_0, a##u##_1, a##u##_2, a##u##_3, a##u##_4, a##u##_5, a##u##_6, a##u##_7;
#define CH_LOAD(u) { const int i = 8 * ty + (u); \
    float4 p0 = *reinterpret_cast<const float4*>(&A[i * NC + 4 * tx]); \
    float4 p1 = *reinterpret_cast<const float4*>(&A[i * NC + 4 * tx + 128]); \
    a##u##_0 = p0.x; a##u##_1 = p0.y; a##u##_2 = p0.z; a##u##_3 = p0.w; \
    a##u##_4 = p1.x; a##u##_5 = p1.y; a##u##_6 = p1.z; a##u##_7 = p1.w; }
#define CH_SEED(u) { const int i = 8 * ty + (u); \
    colbuf[0][i] = (i == 0) ? 0.f : a##u##_0; if (i == 0) colbuf[0][NC] = a##u##_0; }
#define CH_UPD(u, ru) \
    a##u##_0 = fmaf(-(ru), d0.x, a##u##_0); a##u##_1 = fmaf(-(ru), d0.y, a##u##_1); \
    a##u##_2 = fmaf(-(ru), d0.z, a##u##_2); a##u##_3 = fmaf(-(ru), d0.w, a##u##_3); \
    a##u##_4 = fmaf(-(ru), d1.x, a##u##_4); a##u##_5 = fmaf(-(ru), d1.y, a##u##_5); \
    a##u##_6 = fmaf(-(ru), d1.z, a##u##_6); a##u##_7 = fmaf(-(ru), d1.w, a##u##_7);
#define CH_SCALE(u, v) { const int i = 8 * ty + (u); \
    if (i >= k) { const float val = (i == k) ? ld : a##u##_##v * inv; a##u##_##v = val; A[i * NC + k] = val; } }
#define CH_SCALE8(v) CH_SCALE(0, v) CH_SCALE(1, v) CH_SCALE(2, v) CH_SCALE(3, v) \
                     CH_SCALE(4, v) CH_SCALE(5, v) CH_SCALE(6, v) CH_SCALE(7, v)
#define CH_STAGE(u, v) { const int i = 8 * ty + (u); \
    colbuf[nb][i] = (i <= kn) ? 0.f : a##u##_##v; if (i == kn) colbuf[nb][NC] = a##u##_##v; }
#define CH_STAGE8(v) CH_STAGE(0, v) CH_STAGE(1, v) CH_STAGE(2, v) CH_STAGE(3, v) \
                     CH_STAGE(4, v) CH_STAGE(5, v) CH_STAGE(6, v) CH_STAGE(7, v)

__global__ __attribute__((amdgpu_flat_work_group_size(1024, 1024), amdgpu_waves_per_eu(4)))
void chol_kernel(float* __restrict__ A)
{
    const int tid = threadIdx.x;
    const int ty = tid >> 5, tx = tid & 31;
    __shared__ float colbuf[2][NC + 1];    // [.][NC] = diag slot

    CH_DECL(0) CH_DECL(1) CH_DECL(2) CH_DECL(3)
    CH_DECL(4) CH_DECL(5) CH_DECL(6) CH_DECL(7)

    CH_LOAD(0) CH_LOAD(1) CH_LOAD(2) CH_LOAD(3)
    CH_LOAD(4) CH_LOAD(5) CH_LOAD(6) CH_LOAD(7)

    // seed: stage column 0 (owner tx==0, v-slot 0)
    if (tx == 0) {
        CH_SEED(0) CH_SEED(1) CH_SEED(2) CH_SEED(3)
        CH_SEED(4) CH_SEED(5) CH_SEED(6) CH_SEED(7)
    }
    __syncthreads();

    for (int k = 0; k < NC; ++k) {
        const int b = k & 1, nb = b ^ 1;
        const float diag = colbuf[b][NC];
        const float ld = sqrtf(diag);
        const float inv = 1.f / ld;
        const float rd = inv * inv;

        float4 c0 = *reinterpret_cast<const float4*>(&colbuf[b][8 * ty]);
        float4 c1 = *reinterpret_cast<const float4*>(&colbuf[b][8 * ty + 4]);
        float4 d0 = *reinterpret_cast<const float4*>(&colbuf[b][4 * tx]);
        float4 d1 = *reinterpret_cast<const float4*>(&colbuf[b][4 * tx + 128]);
        const float r0 = c0.x * rd, r1 = c0.y * rd, r2 = c0.z * rd, r3 = c0.w * rd;
        const float r4 = c1.x * rd, r5 = c1.y * rd, r6 = c1.z * rd, r7 = c1.w * rd;

        // rank-1 update; rows/cols <= k have colbuf==0 -> no-op
        CH_UPD(0, r0) CH_UPD(1, r1) CH_UPD(2, r2) CH_UPD(3, r3)
        CH_UPD(4, r4) CH_UPD(5, r5) CH_UPD(6, r6) CH_UPD(7, r7)

        // owner scales column k in-register and writes L to global
        const int txk = (k & 127) >> 2;
        const int vk = (k & 3) + ((k & 128) ? 4 : 0);
        if (tx == txk) {
            switch (vk) {   // wave-uniform -> scalar branch tree
                case 0: CH_SCALE8(0) break;
                case 1: CH_SCALE8(1) break;
                case 2: CH_SCALE8(2) break;
                case 3: CH_SCALE8(3) break;
                case 4: CH_SCALE8(4) break;
                case 5: CH_SCALE8(5) break;
                case 6: CH_SCALE8(6) break;
                case 7: CH_SCALE8(7) break;
            }
        }
        // stage next column (unscaled, post-update) into the other buffer
        const int kn = k + 1;
        if (kn < NC) {
            const int txn = (kn & 127) >> 2;
            const int vn = (kn & 3) + ((kn & 128) ? 4 : 0);
            if (tx == txn) {
                switch (vn) {
                    case 0: CH_STAGE8(0) break;
                    case 1: CH_STAGE8(1) break;
                    case 2: CH_STAGE8(2) break;
                    case 3: CH_STAGE8(3) break;
                    case 4: CH_STAGE8(4) break;
                    case 5: CH_STAGE8(5) break;
                    case 6: CH_STAGE8(6) break;
                    case 7: CH_STAGE8(7) break;
                }
            }
        }
        __syncthreads();
    }
}

// ---------------- triangular inverse: W = L^{-1} ----------------
// one wave per column; solution vector distributed across lanes (wreg).
__global__ __launch_bounds__(256) void trinv_kernel(const float* __restrict__ L,
                                                    float* __restrict__ W)
{
    const int lane = threadIdx.x & 63;
    const int wv = threadIdx.x >> 6;
    const int j = blockIdx.x * 4 + wv;
    float wreg[4] = {0.f, 0.f, 0.f, 0.f};
    if (lane == 0) wreg[0] = 1.f / L[j * NC + j];
    for (int i = j + 1; i < NC; ++i) {
        float s = 0.f;
#pragma unroll
        for (int c = 0; c < 4; ++c) {
            const int t = j + lane + 64 * c;
            if (t < i) s += L[i * NC + t] * wreg[c];
        }
#pragma unroll
        for (int off = 32; off > 0; off >>= 1) s += __shfl_xor(s, off);
        const float wi = -s / L[i * NC + i];
        const int d = i - j;
        if (lane == (d & 63)) wreg[d >> 6] = wi;
    }
#pragma unroll
    for (int c = 0; c < 4; ++c) {
        const int t = j + lane + 64 * c;
        if (t < NC) W[t * NC + j] = wreg[c];
    }
}

// ---------------- whiten: out = (X - m) @ W^T ----------------
// grid (1024, 2) x 256 threads; 128x128 tile, K chunks of 32, LDS stride 44.
// R5: waves_per_eu(2) -> 256-VGPR budget (live set ~140: 64 acc + 64 xi/xj);
// default 64-budget was spilling half of it.
#define WST 44
__global__ __attribute__((amdgpu_flat_work_group_size(256, 256), amdgpu_waves_per_eu(2)))
void whiten_kernel(
    const float* __restrict__ x, const float* __restrict__ W,
    const float* __restrict__ sums, float* __restrict__ out)
{
    __shared__ float Xt[128 * WST];
    __shared__ float Wt[128 * WST];
    __shared__ float mbuf[NC];
    const int tid = threadIdx.x;
    const int ty = tid >> 4, tx = tid & 15;
    const int row0 = blockIdx.x * 128;
    const int col0 = blockIdx.y * 128;
    mbuf[tid] = sums[tid] * (1.f / (float)NROWS);
    __syncthreads();

    float acc[8][8];
#pragma unroll
    for (int u = 0; u < 8; ++u)
#pragma unroll
        for (int v = 0; v < 8; ++v) acc[u][v] = 0.f;

    for (int k0 = 0; k0 < NC; k0 += 32) {
#pragma unroll
        for (int it = 0; it < 4; ++it) {
            const int idx = tid + 256 * it;
            const int rr = idx >> 3;
            const int kb = (idx & 7) << 2;
            float4 xv = *reinterpret_cast<const float4*>(&x[(size_t)(row0 + rr) * NC + k0 + kb]);
            float4 mv = *reinterpret_cast<const float4*>(&mbuf[k0 + kb]);
            xv.x -= mv.x; xv.y -= mv.y; xv.z -= mv.z; xv.w -= mv.w;
            *reinterpret_cast<float4*>(&Xt[rr * WST + kb]) = xv;
            float4 wv = *reinterpret_cast<const float4*>(&W[(size_t)(col0 + rr) * NC + k0 + kb]);
            *reinterpret_cast<float4*>(&Wt[rr * WST + kb]) = wv;
        }
        __syncthreads();
#pragma unroll
        for (int kb = 0; kb < 32; kb += 4) {
            float4 xi[8], xj[8];
#pragma unroll
            for (int u = 0; u < 8; ++u)
                xi[u] = *reinterpret_cast<const float4*>(&Xt[(8 * ty + u) * WST + kb]);
#pragma unroll
            for (int v = 0; v < 8; ++v) {
                const int jc = 4 * tx + (v & 3) + ((v < 4) ? 0 : 64);
                xj[v] = *reinterpret_cast<const float4*>(&Wt[jc * WST + kb]);
            }
#pragma unroll
            for (int u = 0; u < 8; ++u)
#pragma unroll
                for (int v = 0; v < 8; ++v) {
                    acc[u][v] = fmaf(xi[u].x, xj[v].x, acc[u][v]);
                    acc[u][v] = fmaf(xi[u].y, xj[v].y, acc[u][v]);
                    acc[u][v] = fmaf(xi[u].z, xj[v].z, acc[u][v]);
                    acc[u][v] = fmaf(xi[u].w, xj[v].w, acc[u][v]);
                }
        }
        __syncthreads();
    }
#pragma unroll
    for (int u = 0; u < 8; ++u) {
        const int i = row0 + 8 * ty + u;
#pragma unroll
        for (int q = 0; q < 2; ++q) {
            float4 o;
            o.x = acc[u][4 * q + 0]; o.y = acc[u][4 * q + 1];
            o.z = acc[u][4 * q + 2]; o.w = acc[u][4 * q + 3];
            *reinterpret_cast<float4*>(&out[(size_t)i * NC + col0 + 4 * tx + 64 * q]) = o;
        }
    }
}

extern "C" void kernel_launch(void* const* d_in, const int* in_sizes, int n_in,
                              void* d_out, int out_size, void* d_ws, size_t ws_size,
                              hipStream_t stream)
{
    const float* x = (const float*)d_in[0];
    float* out = (float*)d_out;
    float* S    = (float*)d_ws;        // 65536
    float* sums = S + 65536;           // 256
    float* A    = sums + 256;          // 65536 (cov in, L out)
    float* W    = A + 65536;           // 65536 (L^{-1})

    hipMemsetAsync(S, 0, (65536 + 256) * sizeof(float), stream);
    hipMemsetAsync(W, 0, 65536 * sizeof(float), stream);

    cov_accum_kernel<<<256, 1024, 0, stream>>>(x, S, sums);
    finalize_cov_kernel<<<256, 256, 0, stream>>>(S, sums, A);
    chol_kernel<<<1, 1024, 0, stream>>>(A);
    trinv_kernel<<<64, 256, 0, stream>>>(A, W);
    whiten_kernel<<<dim3(1024, 2), 256, 0, stream>>>(x, W, sums, out);
}

// Round 7
// 1176.649 us; speedup vs baseline: 1.3206x; 1.3206x over previous
//
#include <hip/hip_runtime.h>

#define NROWS 131072   // 32*64*64
#define NC 256
#define EPSV 0.001f

typedef __attribute__((ext_vector_type(4))) float f32x4;
typedef __attribute__((ext_vector_type(8))) short s16x8;

__device__ __forceinline__ unsigned short f2bf(float x) {
    unsigned u = __float_as_uint(x);
    unsigned r = (u + 0x7FFFu + ((u >> 16) & 1u)) >> 16;   // RNE
    return (unsigned short)r;
}
__device__ __forceinline__ float bf2f(unsigned short b) {
    return __uint_as_float(((unsigned)b) << 16);
}

// ================= covariance via split-bf16 MFMA =================
// S = X^T X. x split as hi+lo bf16 (error ~2^-18 rel; lo*lo dropped).
// 3 patches of 128x128 {(0,0),(1,0),(1,1)} x 64 row-chunks = 192 blocks.
// MFMA acc lives in AGPRs -> ~45 live VGPRs (dodges the 64-reg allocator
// pathology that stalled R1-R5). A/B frags use the IDENTICAL (lane,e)->k
// gather, so the result is invariant to the HW k-permutation; row/col =
// lane&15 consistent with the HW-verified C/D mapping (m89).
#define CVS 134   // LDS row stride in bf16 elems (128 + 6 pad) -> 268B = 67 dw

#define MFMA16 __builtin_amdgcn_mfma_f32_16x16x32_bf16

#define LDFRAG(dst, plane, base) { s16x8 _f;                                   \
    _f[0] = (short)plane[(base)];        _f[1] = (short)plane[(base) + 134];   \
    _f[2] = (short)plane[(base) + 268];  _f[3] = (short)plane[(base) + 402];   \
    _f[4] = (short)plane[(base) + 536];  _f[5] = (short)plane[(base) + 670];   \
    _f[6] = (short)plane[(base) + 804];  _f[7] = (short)plane[(base) + 938];   \
    dst = _f; }

__global__ __launch_bounds__(512) void cov_mfma_kernel(
    const float* __restrict__ x, float* __restrict__ S, float* __restrict__ sums)
{
    __shared__ unsigned short Ah[64 * CVS], Al[64 * CVS];
    __shared__ unsigned short Bh[64 * CVS], Bl[64 * CVS];
    const int patch = blockIdx.x >> 6;       // 0,1,2
    const int kc    = blockIdx.x & 63;
    const int pi = (patch == 0) ? 0 : 1;
    const int pj = (patch == 2) ? 1 : 0;
    const bool offdiag = (patch == 1);
    const int cm0 = pi * 128, cn0 = pj * 128;
    const int tid = threadIdx.x;
    const int lane = tid & 63, wid = tid >> 6;
    const int wm = wid >> 2, wn = wid & 3;   // 2x4 wave grid over 128x128
    const int g = lane >> 4, ll = lane & 15;
    const int sc4 = tid & 31;                // staging float4-column (fixed)
    const long rowbase = (long)kc * 2048;

    f32x4 c00 = {0,0,0,0}, c01 = {0,0,0,0}, c10 = {0,0,0,0}, c11 = {0,0,0,0};
    f32x4 c20 = {0,0,0,0}, c21 = {0,0,0,0}, c30 = {0,0,0,0}, c31 = {0,0,0,0};
    float ps0 = 0.f, ps1 = 0.f, ps2 = 0.f, ps3 = 0.f;   // channel partial sums

    const int fb = g * 1072 + ll;            // g*8*134 + ll

    for (int kt = 0; kt < 32; ++kt) {
        __syncthreads();   // previous compute done before LDS overwrite
        const long rbase = rowbase + kt * 64;
#pragma unroll
        for (int it = 0; it < 4; ++it) {
            const int idx = tid + (it << 9);
            const int r = idx >> 5;          // 0..63
            float4 v = *reinterpret_cast<const float4*>(&x[(rbase + r) * NC + cm0 + sc4 * 4]);
            unsigned short h0 = f2bf(v.x), h1 = f2bf(v.y), h2 = f2bf(v.z), h3 = f2bf(v.w);
            unsigned short l0 = f2bf(v.x - bf2f(h0)), l1 = f2bf(v.y - bf2f(h1));
            unsigned short l2 = f2bf(v.z - bf2f(h2)), l3 = f2bf(v.w - bf2f(h3));
            unsigned* dh = (unsigned*)&Ah[r * CVS + sc4 * 4];
            dh[0] = (unsigned)h0 | ((unsigned)h1 << 16);
            dh[1] = (unsigned)h2 | ((unsigned)h3 << 16);
            unsigned* dl = (unsigned*)&Al[r * CVS + sc4 * 4];
            dl[0] = (unsigned)l0 | ((unsigned)l1 << 16);
            dl[1] = (unsigned)l2 | ((unsigned)l3 << 16);
            if (!offdiag) { ps0 += v.x; ps1 += v.y; ps2 += v.z; ps3 += v.w; }
        }
        if (offdiag) {
#pragma unroll
            for (int it = 0; it < 4; ++it) {
                const int idx = tid + (it << 9);
                const int r = idx >> 5;
                float4 v = *reinterpret_cast<const float4*>(&x[(rbase + r) * NC + cn0 + sc4 * 4]);
                unsigned short h0 = f2bf(v.x), h1 = f2bf(v.y), h2 = f2bf(v.z), h3 = f2bf(v.w);
                unsigned short l0 = f2bf(v.x - bf2f(h0)), l1 = f2bf(v.y - bf2f(h1));
                unsigned short l2 = f2bf(v.z - bf2f(h2)), l3 = f2bf(v.w - bf2f(h3));
                unsigned* dh = (unsigned*)&Bh[r * CVS + sc4 * 4];
                dh[0] = (unsigned)h0 | ((unsigned)h1 << 16);
                dh[1] = (unsigned)h2 | ((unsigned)h3 << 16);
                unsigned* dl = (unsigned*)&Bl[r * CVS + sc4 * 4];
                dl[0] = (unsigned)l0 | ((unsigned)l1 << 16);
                dl[1] = (unsigned)l2 | ((unsigned)l3 << 16);
            }
        }
        __syncthreads();
        const unsigned short* bhp = offdiag ? Bh : Ah;
        const unsigned short* blp = offdiag ? Bl : Al;
#pragma unroll
        for (int kb = 0; kb < 2; ++kb) {
            const int kboff = kb * 4288;     // kb*32*134
            s16x8 bh0, bl0, bh1, bl1;
            LDFRAG(bh0, bhp, kboff + (wn * 2 + 0) * 16 + fb);
            LDFRAG(bl0, blp, kboff + (wn * 2 + 0) * 16 + fb);
            LDFRAG(bh1, bhp, kboff + (wn * 2 + 1) * 16 + fb);
            LDFRAG(bl1, blp, kboff + (wn * 2 + 1) * 16 + fb);
#define COV_M(m)                                                               \
            { s16x8 ah, al;                                                    \
              LDFRAG(ah, Ah, kboff + (wm * 4 + m) * 16 + fb);                  \
              LDFRAG(al, Al, kboff + (wm * 4 + m) * 16 + fb);                  \
              c##m##0 = MFMA16(ah, bh0, c##m##0, 0, 0, 0);                     \
              c##m##0 = MFMA16(ah, bl0, c##m##0, 0, 0, 0);                     \
              c##m##0 = MFMA16(al, bh0, c##m##0, 0, 0, 0);                     \
              c##m##1 = MFMA16(ah, bh1, c##m##1, 0, 0, 0);                     \
              c##m##1 = MFMA16(ah, bl1, c##m##1, 0, 0, 0);                     \
              c##m##1 = MFMA16(al, bh1, c##m##1, 0, 0, 0); }
            COV_M(0) COV_M(1) COV_M(2) COV_M(3)
#undef COV_M
        }
    }
    // C/D layout (m89): col = lane&15, row = (lane>>4)*4 + reg
#define COV_WR(m, n)                                                           \
    { const int rg = cm0 + (wm * 4 + m) * 16 + g * 4;                          \
      const int cg = cn0 + (wn * 2 + n) * 16 + ll;                             \
      atomicAdd(&S[(rg + 0) * NC + cg], c##m##n[0]);                           \
      atomicAdd(&S[(rg + 1) * NC + cg], c##m##n[1]);                           \
      atomicAdd(&S[(rg + 2) * NC + cg], c##m##n[2]);                           \
      atomicAdd(&S[(rg + 3) * NC + cg], c##m##n[3]); }
    COV_WR(0,0) COV_WR(0,1) COV_WR(1,0) COV_WR(1,1)
    COV_WR(2,0) COV_WR(2,1) COV_WR(3,0) COV_WR(3,1)
#undef COV_WR
    if (!offdiag) {
        atomicAdd(&sums[cm0 + sc4 * 4 + 0], ps0);
        atomicAdd(&sums[cm0 + sc4 * 4 + 1], ps1);
        atomicAdd(&sums[cm0 + sc4 * 4 + 2], ps2);
        atomicAdd(&sums[cm0 + sc4 * 4 + 3], ps3);
    }
}

// ---------------- finalize covariance ----------------
__global__ void finalize_cov_kernel(const float* __restrict__ S,
                                    const float* __restrict__ sums,
                                    float* __restrict__ A)
{
    const int i = blockIdx.x;
    const int j = threadIdx.x;
    const float n = (float)NROWS;
    const float sv = (i >= j) ? S[i * NC + j] : S[j * NC + i];
    float c = (sv - sums[i] * sums[j] / n) / (n - 1.f);
    c *= (1.f - EPSV);
    if (i == j) c += EPSV;
    A[i * NC + j] = c;
}

// ================= blocked Cholesky (panel in LDS) =================
// R6 structural fix: NO per-thread register tile (R1-R5 proved the allocator
// pins kernels at <=64 VGPR and shuffles the overflow at ~4x VALU cost).
// Panel of 32 columns factorized with float4 LDS read-modify-write; trailing
// update A -= L.L^T from a transposed LDS copy Pt with 4x4 reg tiles
// (~40 live VGPRs). 512 threads: waves 0..3 run the panel (rows = tid),
// all 8 waves run the trailing patches.
#define PST 36     // P row stride (f32): 144B, 16B-aligned
#define PTST 264   // Pt row stride (f32)
__global__ __launch_bounds__(512) void chol_blocked_kernel(float* __restrict__ A)
{
    __shared__ float P[256 * PST];    // panel [256 rows][32 cols+pad]
    __shared__ float Pt[32 * PTST];   // scaled panel transposed [32][256+pad]
    __shared__ float rs[32];
    const int tid = threadIdx.x;

    for (int p = 0; p < 8; ++p) {
        const int p0 = p * 32, H = 256 - p0;
        // ---- load panel ----
        if (tid < H) {
#pragma unroll
            for (int j = 0; j < 8; ++j)
                *reinterpret_cast<float4*>(&P[tid * PST + 4 * j]) =
                    *reinterpret_cast<const float4*>(&A[(p0 + tid) * NC + p0 + 4 * j]);
        }
        __syncthreads();
        // ---- 32 micro-steps ----
        for (int k = 0; k < 32; ++k) {
            if (tid < H) {
                const float d = P[k * PST + k];
                const float rd = 1.0f / d;
                const float ard = P[tid * PST + k] * rd;
                if (tid == 0) rs[k] = 1.0f / sqrtf(d);
#pragma unroll
                for (int j = 0; j < 8; ++j) {
                    float4 rw = *reinterpret_cast<float4*>(&P[tid * PST + 4 * j]);
                    const float t0 = P[(4 * j + 0) * PST + k];
                    const float t1 = P[(4 * j + 1) * PST + k];
                    const float t2 = P[(4 * j + 2) * PST + k];
                    const float t3 = P[(4 * j + 3) * PST + k];
                    rw.x -= (4 * j + 0 > k) ? ard * t0 : 0.f;
                    rw.y -= (4 * j + 1 > k) ? ard * t1 : 0.f;
                    rw.z -= (4 * j + 2 > k) ? ard * t2 : 0.f;
                    rw.w -= (4 * j + 3 > k) ? ard * t3 : 0.f;
                    *reinterpret_cast<float4*>(&P[tid * PST + 4 * j]) = rw;
                }
            }
            __syncthreads();
        }
        // ---- scale, write L to global, build transposed Pt ----
        if (tid < H) {
            const int ig = p0 + tid;
#pragma unroll
            for (int j = 0; j < 8; ++j) {
                float4 rw = *reinterpret_cast<float4*>(&P[tid * PST + 4 * j]);
                rw.x *= rs[4 * j + 0]; rw.y *= rs[4 * j + 1];
                rw.z *= rs[4 * j + 2]; rw.w *= rs[4 * j + 3];
                Pt[(4 * j + 0) * PTST + tid] = rw.x;
                Pt[(4 * j + 1) * PTST + tid] = rw.y;
                Pt[(4 * j + 2) * PTST + tid] = rw.z;
                Pt[(4 * j + 3) * PTST + tid] = rw.w;
                if (4 * j + 0 <= tid) A[ig * NC + p0 + 4 * j + 0] = rw.x;
                if (4 * j + 1 <= tid) A[ig * NC + p0 + 4 * j + 1] = rw.y;
                if (4 * j + 2 <= tid) A[ig * NC + p0 + 4 * j + 2] = rw.z;
                if (4 * j + 3 <= tid) A[ig * NC + p0 + 4 * j + 3] = rw.w;
            }
        }
        __syncthreads();
        // ---- trailing update: A[i][j] -= sum_k L[i][k]*L[j][k] ----
        const int r0 = p0 + 32;
        const int gb = (256 - r0 + 63) >> 6;   // 64-wide patch grid
        const int sub = tid >> 8;              // wave-half handles alternate patches
        const int ty = (tid & 255) >> 4, tx = tid & 15;
        int q = 0;
        for (int bi = 0; bi < gb; ++bi) {
            for (int bj = 0; bj <= bi; ++bj) {
                if ((q++ & 1) != sub) continue;
                const int i0 = r0 + bi * 64 + ty * 4;
                const int j0 = r0 + bj * 64 + tx * 4;
                if (i0 >= 256 || j0 >= 256) continue;
                const int reli = i0 - p0, relj = j0 - p0;
                float4 a0 = {0,0,0,0}, a1 = {0,0,0,0}, a2 = {0,0,0,0}, a3 = {0,0,0,0};
#pragma unroll 4
                for (int k = 0; k < 32; ++k) {
                    const float4 av = *reinterpret_cast<const float4*>(&Pt[k * PTST + reli]);
                    const float4 bv = *reinterpret_cast<const float4*>(&Pt[k * PTST + relj]);
                    a0.x += av.x * bv.x; a0.y += av.x * bv.y; a0.z += av.x * bv.z; a0.w += av.x * bv.w;
                    a1.x += av.y * bv.x; a1.y += av.y * bv.y; a1.z += av.y * bv.z; a1.w += av.y * bv.w;
                    a2.x += av.z * bv.x; a2.y += av.z * bv.y; a2.z += av.z * bv.z; a2.w += av.z * bv.w;
                    a3.x += av.w * bv.x; a3.y += av.w * bv.y; a3.z += av.w * bv.z; a3.w += av.w * bv.w;
                }
                float4* g0 = reinterpret_cast<float4*>(&A[(i0 + 0) * NC + j0]);
                float4* g1 = reinterpret_cast<float4*>(&A[(i0 + 1) * NC + j0]);
                float4* g2 = reinterpret_cast<float4*>(&A[(i0 + 2) * NC + j0]);
                float4* g3 = reinterpret_cast<float4*>(&A[(i0 + 3) * NC + j0]);
                float4 v0 = *g0, v1 = *g1, v2 = *g2, v3 = *g3;
                v0.x -= a0.x; v0.y -= a0.y; v0.z -= a0.z; v0.w -= a0.w;
                v1.x -= a1.x; v1.y -= a1.y; v1.z -= a1.z; v1.w -= a1.w;
                v2.x -= a2.x; v2.y -= a2.y; v2.z -= a2.z; v2.w -= a2.w;
                v3.x -= a3.x; v3.y -= a3.y; v3.z -= a3.z; v3.w -= a3.w;
                *g0 = v0; *g1 = v1; *g2 = v2; *g3 = v3;
            }
        }
        __syncthreads();
    }
}

// ---------------- triangular inverse: W = L^{-1} ----------------
__global__ __launch_bounds__(256) void trinv_kernel(const float* __restrict__ L,
                                                    float* __restrict__ W)
{
    const int lane = threadIdx.x & 63;
    const int wv = threadIdx.x >> 6;
    const int j = blockIdx.x * 4 + wv;
    float wreg[4] = {0.f, 0.f, 0.f, 0.f};
    if (lane == 0) wreg[0] = 1.f / L[j * NC + j];
    for (int i = j + 1; i < NC; ++i) {
        float s = 0.f;
#pragma unroll
        for (int c = 0; c < 4; ++c) {
            const int t = j + lane + 64 * c;
            if (t < i) s += L[i * NC + t] * wreg[c];
        }
#pragma unroll
        for (int off = 32; off > 0; off >>= 1) s += __shfl_xor(s, off);
        const float wi = -s / L[i * NC + i];
        const int d = i - j;
        if (lane == (d & 63)) wreg[d >> 6] = wi;
    }
#pragma unroll
    for (int c = 0; c < 4; ++c) {
        const int t = j + lane + 64 * c;
        if (t < NC) W[t * NC + j] = wreg[c];
    }
}

// ---------------- whiten: out = (X - m) @ W^T (unchanged this round) -------
#define WST 44
__global__ __attribute__((amdgpu_flat_work_group_size(256, 256), amdgpu_waves_per_eu(2)))
void whiten_kernel(
    const float* __restrict__ x, const float* __restrict__ W,
    const float* __restrict__ sums, float* __restrict__ out)
{
    __shared__ float Xt[128 * WST];
    __shared__ float Wt[128 * WST];
    __shared__ float mbuf[NC];
    const int tid = threadIdx.x;
    const int ty = tid >> 4, tx = tid & 15;
    const int row0 = blockIdx.x * 128;
    const int col0 = blockIdx.y * 128;
    mbuf[tid] = sums[tid] * (1.f / (float)NROWS);
    __syncthreads();

    float acc[8][8];
#pragma unroll
    for (int u = 0; u < 8; ++u)
#pragma unroll
        for (int v = 0; v < 8; ++v) acc[u][v] = 0.f;

    for (int k0 = 0; k0 < NC; k0 += 32) {
#pragma unroll
        for (int it = 0; it < 4; ++it) {
            const int idx = tid + 256 * it;
            const int rr = idx >> 3;
            const int kb = (idx & 7) << 2;
            float4 xv = *reinterpret_cast<const float4*>(&x[(size_t)(row0 + rr) * NC + k0 + kb]);
            float4 mv = *reinterpret_cast<const float4*>(&mbuf[k0 + kb]);
            xv.x -= mv.x; xv.y -= mv.y; xv.z -= mv.z; xv.w -= mv.w;
            *reinterpret_cast<float4*>(&Xt[rr * WST + kb]) = xv;
            float4 wv = *reinterpret_cast<const float4*>(&W[(size_t)(col0 + rr) * NC + k0 + kb]);
            *reinterpret_cast<float4*>(&Wt[rr * WST + kb]) = wv;
        }
        __syncthreads();
#pragma unroll
        for (int kb = 0; kb < 32; kb += 4) {
            float4 xi[8], xj[8];
#pragma unroll
            for (int u = 0; u < 8; ++u)
                xi[u] = *reinterpret_cast<const float4*>(&Xt[(8 * ty + u) * WST + kb]);
#pragma unroll
            for (int v = 0; v < 8; ++v) {
                const int jc = 4 * tx + (v & 3) + ((v < 4) ? 0 : 64);
                xj[v] = *reinterpret_cast<const float4*>(&Wt[jc * WST + kb]);
            }
#pragma unroll
            for (int u = 0; u < 8; ++u)
#pragma unroll
                for (int v = 0; v < 8; ++v) {
                    acc[u][v] = fmaf(xi[u].x, xj[v].x, acc[u][v]);
                    acc[u][v] = fmaf(xi[u].y, xj[v].y, acc[u][v]);
                    acc[u][v] = fmaf(xi[u].z, xj[v].z, acc[u][v]);
                    acc[u][v] = fmaf(xi[u].w, xj[v].w, acc[u][v]);
                }
        }
        __syncthreads();
    }
#pragma unroll
    for (int u = 0; u < 8; ++u) {
        const int i = row0 + 8 * ty + u;
#pragma unroll
        for (int q = 0; q < 2; ++q) {
            float4 o;
            o.x = acc[u][4 * q + 0]; o.y = acc[u][4 * q + 1];
            o.z = acc[u][4 * q + 2]; o.w = acc[u][4 * q + 3];
            *reinterpret_cast<float4*>(&out[(size_t)i * NC + col0 + 4 * tx + 64 * q]) = o;
        }
    }
}

extern "C" void kernel_launch(void* const* d_in, const int* in_sizes, int n_in,
                              void* d_out, int out_size, void* d_ws, size_t ws_size,
                              hipStream_t stream)
{
    const float* x = (const float*)d_in[0];
    float* out = (float*)d_out;
    float* S    = (float*)d_ws;        // 65536
    float* sums = S + 65536;           // 256
    float* A    = sums + 256;          // 65536 (cov in, L out)
    float* W    = A + 65536;           // 65536 (L^{-1})

    hipMemsetAsync(S, 0, (65536 + 256) * sizeof(float), stream);
    hipMemsetAsync(W, 0, 65536 * sizeof(float), stream);

    cov_mfma_kernel<<<192, 512, 0, stream>>>(x, S, sums);
    finalize_cov_kernel<<<256, 256, 0, stream>>>(S, sums, A);
    chol_blocked_kernel<<<1, 512, 0, stream>>>(A);
    trinv_kernel<<<64, 256, 0, stream>>>(A, W);
    whiten_kernel<<<dim3(1024, 2), 256, 0, stream>>>(x, W, sums, out);
}